// Round 2
// baseline (321.637 us; speedup 1.0000x reference)
//
#include <hip/hip_runtime.h>
#include <math.h>

#define D 4096
#define E_EXPERTS 64
#define NTOK 32768
#define BM 128
#define BK 32
#define NTHREADS 256
#define AS_LD (BM + 4)        /* 132 */
#define BS_LD (E_EXPERTS + 4) /* 68 */
#define L_LD (E_EXPERTS + 1)  /* 65 */
#define SMEM_FLOATS 8712
#define TAU 2.5e-4f

// out layout (float32):
//   [0,65536)          top_k_indices as float
//   [65536,131072)     top_k_weights
//   [131072]           balance_loss
//   [131073]           z_loss
//   [131074,131138)    tokens_per_expert
// ws layout (float32): [0,64) counts, [64,128) prob sums, [128] lse sum

__global__ __launch_bounds__(NTHREADS)
void moe_router_main(const float* __restrict__ x,
                     const float* __restrict__ gw,
                     float* __restrict__ out,
                     float* __restrict__ ws) {
  __shared__ float smem[SMEM_FLOATS];
  float* As = smem;                   // [BK][AS_LD] transposed A tile
  float* Bs = smem + BK * AS_LD;      // [BK][BS_LD] transposed W tile

  const int tid = threadIdx.x;
  const int bid = blockIdx.x;
  const int t0 = bid * BM;

  const int tm0 = (tid >> 4) << 3;    // 8 tokens per thread
  const int tn0 = (tid & 15) << 2;    // 4 experts per thread

  float acc[8][4];
#pragma unroll
  for (int i = 0; i < 8; ++i)
#pragma unroll
    for (int j = 0; j < 4; ++j) acc[i][j] = 0.0f;

  const float* xA = x + (size_t)t0 * D;

  float4 pa[4];
  float4 pb[2];
  int aRow[4], aCol[4], bRow[2], bCol[2];
#pragma unroll
  for (int r = 0; r < 4; ++r) {
    int idx = tid + r * NTHREADS;
    aRow[r] = idx >> 3;
    aCol[r] = (idx & 7) << 2;
    pa[r] = *(const float4*)(xA + (size_t)aRow[r] * D + aCol[r]);
  }
#pragma unroll
  for (int r = 0; r < 2; ++r) {
    int idx = tid + r * NTHREADS;
    bRow[r] = idx >> 3;
    bCol[r] = (idx & 7) << 2;
    pb[r] = *(const float4*)(gw + (size_t)bRow[r] * D + bCol[r]);
  }

  const int NKT = D / BK;  // 128
  for (int kt = 0; kt < NKT; ++kt) {
    // store prefetched tile to LDS (transposed)
#pragma unroll
    for (int r = 0; r < 4; ++r) {
      float* p = As + aCol[r] * AS_LD + aRow[r];
      p[0 * AS_LD] = pa[r].x;
      p[1 * AS_LD] = pa[r].y;
      p[2 * AS_LD] = pa[r].z;
      p[3 * AS_LD] = pa[r].w;
    }
#pragma unroll
    for (int r = 0; r < 2; ++r) {
      float* p = Bs + bCol[r] * BS_LD + bRow[r];
      p[0 * BS_LD] = pb[r].x;
      p[1 * BS_LD] = pb[r].y;
      p[2 * BS_LD] = pb[r].z;
      p[3 * BS_LD] = pb[r].w;
    }
    __syncthreads();

    // issue next-tile global loads (hide HBM latency under the FMA block)
    if (kt + 1 < NKT) {
      const int k0 = (kt + 1) * BK;
#pragma unroll
      for (int r = 0; r < 4; ++r)
        pa[r] = *(const float4*)(xA + (size_t)aRow[r] * D + k0 + aCol[r]);
#pragma unroll
      for (int r = 0; r < 2; ++r)
        pb[r] = *(const float4*)(gw + (size_t)bRow[r] * D + k0 + bCol[r]);
    }

    // compute current tile
#pragma unroll
    for (int kk = 0; kk < BK; ++kk) {
      float4 a0 = *(const float4*)(As + kk * AS_LD + tm0);
      float4 a1 = *(const float4*)(As + kk * AS_LD + tm0 + 4);
      float4 bv = *(const float4*)(Bs + kk * BS_LD + tn0);
      float a[8] = {a0.x, a0.y, a0.z, a0.w, a1.x, a1.y, a1.z, a1.w};
      float b[4] = {bv.x, bv.y, bv.z, bv.w};
#pragma unroll
      for (int i = 0; i < 8; ++i)
#pragma unroll
        for (int j = 0; j < 4; ++j)
          acc[i][j] = fmaf(a[i], b[j], acc[i][j]);
    }
    __syncthreads();
  }

  // ---------------- epilogue: logits -> LDS, per-token stats ----------------
  float* L = smem;                       // [BM][L_LD]
  float* mArr = smem + BM * L_LD;        // [BM]
  float* zArr = mArr + BM;               // [BM] holds 1/Z
  float* cntL = zArr + BM;               // [E]
  float* probA = cntL + E_EXPERTS;       // [E]
  float* red = probA + E_EXPERTS;        // [8]

#pragma unroll
  for (int i = 0; i < 8; ++i)
#pragma unroll
    for (int j = 0; j < 4; ++j)
      L[(tm0 + i) * L_LD + tn0 + j] = acc[i][j];
  if (tid < E_EXPERTS) {
    cntL[tid] = 0.0f;
    probA[tid] = 0.0f;
  }
  __syncthreads();

  float lseVal = 0.0f;
  if (tid < BM) {
    const int lane = tid & 63;
    const float* row = L + tid * L_LD;
    // top-3 scan (jax top_k tie-break: lower index first)
    float m1 = -3.4e38f, m2 = -3.4e38f, m3 = -3.4e38f;
    int i1 = 0, i2 = 0, i3 = 0;
    for (int e = 0; e < E_EXPERTS; ++e) {
      float v = row[e];
      if (v > m1) {
        m3 = m2; i3 = i2;
        m2 = m1; i2 = i1;
        m1 = v;  i1 = e;
      } else if (v > m2) {
        m3 = m2; i3 = i2;
        m2 = v;  i2 = e;
      } else if (v > m3) {
        m3 = v; i3 = e;
      }
    }
    float z = 0.0f;
    for (int e = 0; e < E_EXPERTS; ++e) z += __expf(row[e] - m1);
    mArr[tid] = m1;
    zArr[tid] = 1.0f / z;
    lseVal = m1 + logf(z);

    // ---- fp64 refinement of near-ties (wave-cooperative, rare) ----
    bool risky = (m1 - m2 < TAU) || (m2 - m3 < TAU);
    double r1 = 0.0, r2 = 0.0, r3 = 0.0;
    unsigned long long mask = __ballot(risky);
    while (mask) {
      int src = __ffsll((long long)mask) - 1;
      mask &= (mask - 1);
      int tok = t0 + (tid & ~63) + src;
      int j1 = __shfl(i1, src, 64);
      int j2 = __shfl(i2, src, 64);
      int j3 = __shfl(i3, src, 64);
      const float* xr = x + (size_t)tok * D;
      const float* g1 = gw + (size_t)j1 * D;
      const float* g2 = gw + (size_t)j2 * D;
      const float* g3 = gw + (size_t)j3 * D;
      double a1 = 0.0, a2 = 0.0, a3 = 0.0;
      for (int k = lane * 4; k < D; k += 256) {
        float4 xv = *(const float4*)(xr + k);
        float4 w1 = *(const float4*)(g1 + k);
        float4 w2 = *(const float4*)(g2 + k);
        float4 w3 = *(const float4*)(g3 + k);
        a1 += (double)xv.x * w1.x + (double)xv.y * w1.y +
              (double)xv.z * w1.z + (double)xv.w * w1.w;
        a2 += (double)xv.x * w2.x + (double)xv.y * w2.y +
              (double)xv.z * w2.z + (double)xv.w * w2.w;
        a3 += (double)xv.x * w3.x + (double)xv.y * w3.y +
              (double)xv.z * w3.z + (double)xv.w * w3.w;
      }
#pragma unroll
      for (int off = 32; off > 0; off >>= 1) {
        a1 += __shfl_down(a1, off, 64);
        a2 += __shfl_down(a2, off, 64);
        a3 += __shfl_down(a3, off, 64);
      }
      a1 = __shfl(a1, 0, 64);
      a2 = __shfl(a2, 0, 64);
      a3 = __shfl(a3, 0, 64);
      if (lane == src) { r1 = a1; r2 = a2; r3 = a3; }
    }

    float wOut1, wOut2;
    if (risky) {
      double v[3] = {r1, r2, r3};
      int ix[3] = {i1, i2, i3};
#define SORT_SWAP(a, b)                                                  \
      if (v[b] > v[a] || (v[b] == v[a] && ix[b] < ix[a])) {              \
        double tv = v[a]; v[a] = v[b]; v[b] = tv;                        \
        int ti = ix[a]; ix[a] = ix[b]; ix[b] = ti;                       \
      }
      SORT_SWAP(0, 1);
      SORT_SWAP(1, 2);
      SORT_SWAP(0, 1);
#undef SORT_SWAP
      i1 = ix[0]; i2 = ix[1];
      double d = exp(v[1] - v[0]);
      wOut1 = (float)(1.0 / (1.0 + d));
      wOut2 = (float)(d / (1.0 + d));
    } else {
      float e2 = __expf(m2 - m1);
      wOut1 = 1.0f / (1.0f + e2);
      wOut2 = e2 * wOut1;
    }

    size_t ot = ((size_t)t0 + tid) * 2;
    out[ot] = (float)i1;
    out[ot + 1] = (float)i2;
    out[(size_t)NTOK * 2 + ot] = wOut1;
    out[(size_t)NTOK * 2 + ot + 1] = wOut2;

    atomicAdd(&cntL[i1], 1.0f);
    atomicAdd(&cntL[i2], 1.0f);
  }

  // block lse sum
  float v = lseVal;
#pragma unroll
  for (int off = 32; off > 0; off >>= 1) v += __shfl_down(v, off, 64);
  if ((tid & 63) == 0) red[tid >> 6] = v;
  __syncthreads();
  if (tid == 0) atomicAdd(&ws[128], red[0] + red[1] + red[2] + red[3]);
  if (tid < E_EXPERTS) atomicAdd(&ws[tid], cntL[tid]);

  // per-expert prob sums: thread (e, q) sums 32 tokens
  {
    const int e = tid & 63;
    const int q = tid >> 6;
    float s = 0.0f;
    for (int t = q * 32; t < q * 32 + 32; ++t)
      s += __expf(L[t * L_LD + e] - mArr[t]) * zArr[t];
    atomicAdd(&probA[e], s);
  }
  __syncthreads();
  if (tid < E_EXPERTS) atomicAdd(&ws[64 + tid], probA[tid]);
}

__global__ void moe_finalize(const float* __restrict__ ws,
                             float* __restrict__ out) {
  const int e = threadIdx.x;  // 64 threads
  const float inv_n = 1.0f / (float)NTOK;
  float tpe = ws[e] * inv_n;
  out[131074 + e] = tpe;
  float rppe = ws[64 + e] * inv_n;
  float part = tpe * rppe;
#pragma unroll
  for (int off = 32; off > 0; off >>= 1) part += __shfl_down(part, off, 64);
  if (e == 0) {
    out[131072] = part * 64.0f * 0.01f;
    float meanLse = ws[128] * inv_n;
    out[131073] = meanLse * meanLse * 0.001f;
  }
}

extern "C" void kernel_launch(void* const* d_in, const int* in_sizes, int n_in,
                              void* d_out, int out_size, void* d_ws, size_t ws_size,
                              hipStream_t stream) {
  const float* x = (const float*)d_in[0];
  const float* gw = (const float*)d_in[1];
  float* out = (float*)d_out;
  float* ws = (float*)d_ws;

  hipMemsetAsync(d_ws, 0, 129 * sizeof(float), stream);
  hipLaunchKernelGGL(moe_router_main, dim3(NTOK / BM), dim3(NTHREADS), 0, stream,
                     x, gw, out, ws);
  hipLaunchKernelGGL(moe_finalize, dim3(1), dim3(E_EXPERTS), 0, stream, ws, out);
}